// Round 15
// baseline (84.601 us; speedup 1.0000x reference)
//
#include <hip/hip_runtime.h>
#include <hip/hip_bf16.h>

#define TASKS 16
#define DIM 1024
#define HID 128
#define NCLS 10
#define NB 65536
#define BM 128
#define NTILES (NB / BM + TASKS) // 528 = 8 * 66

// ws layout (ints):
//  [0, 16)                      per-task cursors (zeroed by memsetAsync; totals after k_prep)
//  [64, 64 + 16*NB)             rowIdx, per-task capacity NB
//  [64 + 16*NB, ...) shorts:    W1s [T][32 kt'][8KB: [4 kslot][128 col][16B]] (4MB),
//                               then W2t [T][16][128] bf16
#define WS_RIDX 64
#define WS_W1S  (WS_RIDX + 16 * NB)

typedef __attribute__((ext_vector_type(8))) short bf16x8;
typedef __attribute__((ext_vector_type(4))) float f32x4;
typedef __attribute__((ext_vector_type(2))) unsigned u32x2;

__device__ __forceinline__ unsigned short f2bf(float f) {
    union { __hip_bfloat16 h; unsigned short s; } u; u.h = __float2bfloat16(f); return u.s;
}

// ---- pass 1 (single prep kernel): scatter || W1 tiles || W2 ----
__global__ __launch_bounds__(256) void k_prep(const int* __restrict__ tid_arr,
                                              const float* __restrict__ W1,
                                              const float* __restrict__ W2,
                                              int* __restrict__ ws) {
    const int blk = blockIdx.x, tid = threadIdx.x;
    if (blk < 256) {
        // scatter: LDS hist -> one global atomicAdd per task -> ranked write.
        // Order nondeterministic but output values/locations order-independent.
        __shared__ int l[TASKS], base[TASKS];
        if (tid < TASKS) l[tid] = 0;
        __syncthreads();
        const int i = blk * 256 + tid;
        const int t = tid_arr[i];
        const int rank = atomicAdd(&l[t], 1);
        __syncthreads();
        if (tid < TASKS && l[tid] > 0) base[tid] = atomicAdd(&ws[tid], l[tid]);
        __syncthreads();
        ws[WS_RIDX + t * NB + base[t] + rank] = i;
    } else if (blk < 768) {
        // 8KB tile per (t,kt'): [kslot 4][col 128][16B]; k = kt'*32 + kslot*8 + j
        const int idx = blk - 256;
        const int t = idx >> 5, kt = idx & 31;
        __shared__ float ld[32 * 132];
        const float* src = W1 + ((size_t)t * DIM + kt * 32) * HID;
        #pragma unroll
        for (int r = 0; r < 16; ++r) {
            const int fl = r * 256 + tid;
            ld[(fl >> 7) * 132 + (fl & 127)] = src[fl];
        }
        __syncthreads();
        char* dst = (char*)((short*)(ws + WS_W1S) + ((size_t)(t * 32 + kt) << 12));
        #pragma unroll
        for (int g = 0; g < 2; ++g) {
            const int p = tid * 32 + g * 16;
            const int kslot = p >> 11, col = (p >> 4) & 127;
            bf16x8 v;
            #pragma unroll
            for (int j = 0; j < 8; ++j)
                v[j] = (short)f2bf(ld[(kslot * 8 + j) * 132 + col]);
            *(bf16x8*)(dst + p) = v;
        }
    } else {
        const int t = blk - 768;
        short* W2t = (short*)(ws + WS_W1S) + ((size_t)TASKS * 32 * 4096);
        #pragma unroll
        for (int i = 0; i < 8; ++i) {
            const int o = i * 256 + tid, c = o >> 7, h = o & 127;
            const float v = (c < NCLS) ? W2[((size_t)t * HID + h) * NCLS + c] : 0.f;
            W2t[((size_t)t * 16 + c) * HID + h] = (short)f2bf(v);
        }
    }
}

// ---- pass 2: fused grouped GEMM; BK=128 (512B row bursts), B direct from L2 ----
__global__ __launch_bounds__(512, 4) void k_main(
    const float* __restrict__ x, const float* __restrict__ b1,
    const float* __restrict__ b2, const int* __restrict__ ws,
    float* __restrict__ out)
{
    // A dbuf: 2 x 32KB, [16 kslot][128 row][16B] per buf; epilogue reuses buf0 as hl[128][256B]
    __shared__ __align__(16) char smem[65536];
    __shared__ int ridx[BM];

    const int* tot = ws;
    const int* rowIdx = ws + WS_RIDX;
    const short* W1s = (const short*)(ws + WS_W1S);
    const short* W2t = W1s + ((size_t)TASKS * 32 * 4096);

    const int w = (blockIdx.x & 7) * (NTILES / 8) + (blockIdx.x >> 3);

    int t = -1, m = 0, tileInT = 0;
    {
        int accT = 0;
        for (int k = 0; k < TASKS; ++k) {
            const int c = tot[k], nt = (c + BM - 1) >> 7;
            if (t < 0 && w < accT + nt) {
                t = k; tileInT = w - accT;
                m = c - tileInT * BM; if (m > BM) m = BM;
            }
            accT += nt;
        }
    }
    if (t < 0) return;

    const int tid = threadIdx.x;
    if (tid < BM) {
        const int rr = tid < m ? tid : m - 1;
        ridx[tid] = rowIdx[t * NB + tileInT * BM + rr];
    }
    __syncthreads();

    const int lane = tid & 63, wv = tid >> 6;          // 8 waves
    const int lg = lane >> 4, lr = lane & 15;
    const int rh = wv & 1, cq = wv >> 1;
    const int wrow = rh * 64, wcol = cq * 32;

    // A staging: wave rows wv*16..+15; lane: rows ar, ar+8, 16B piece pc of each
    // 128B sub-chunk j. Per row per iter: 4 back-to-back instrs = 512B contiguous.
    const int ar = wv * 16 + (lane >> 3);
    const int pc = lane & 7;
    const float* srcA0 = x + ((size_t)ridx[ar] << 10) + pc * 4;
    const float* srcA1 = x + ((size_t)ridx[ar + 8] << 10) + pc * 4;
    const char* w1sT = (const char*)W1s + ((size_t)t << 18);
    const unsigned bbase = (unsigned)(lg * 2048 + ((wcol + lr) << 4));

    f32x4 aR[8];
    bf16x8 bR[8];
    f32x4 acc[4][2] = {};

    auto LOADA = [&](int kt) {
        #pragma unroll
        for (int j = 0; j < 4; ++j) {
            aR[j]     = *(const f32x4*)(srcA0 + kt * 128 + j * 32);
            aR[4 + j] = *(const f32x4*)(srcA1 + kt * 128 + j * 32);
        }
    };
    auto ISSUEB = [&](int kt) {
        #pragma unroll
        for (int s = 0; s < 4; ++s)
            #pragma unroll
            for (int cf = 0; cf < 2; ++cf)
                bR[s * 2 + cf] = *(const bf16x8*)(
                    w1sT + (size_t)(kt * 4 + s) * 8192 + bbase + cf * 256);
    };
    auto CVTWRITE = [&](int buf) {
        char* ab = smem + buf * 32768;
        #pragma unroll
        for (int j = 0; j < 4; ++j) {
            // piece (j,pc): k_local = j*32 + pc*4 + e -> kslot j*4+(pc>>1), byte (pc&1)*8
            const unsigned base = (unsigned)((j * 4 + (pc >> 1)) * 2048 + (pc & 1) * 8);
            u32x2 p0, p1;
            p0[0] = ((unsigned)f2bf(aR[j][1]) << 16) | f2bf(aR[j][0]);
            p0[1] = ((unsigned)f2bf(aR[j][3]) << 16) | f2bf(aR[j][2]);
            p1[0] = ((unsigned)f2bf(aR[4 + j][1]) << 16) | f2bf(aR[4 + j][0]);
            p1[1] = ((unsigned)f2bf(aR[4 + j][3]) << 16) | f2bf(aR[4 + j][2]);
            *(u32x2*)(ab + base + ar * 16) = p0;             // ds_write_b64
            *(u32x2*)(ab + base + (ar + 8) * 16) = p1;
        }
    };
    auto COMPUTE = [&](int buf) {
        const char* ab = smem + buf * 32768;
        #pragma unroll
        for (int s = 0; s < 4; ++s) {
            const int koff = (s * 4 + lg) * 2048;
            bf16x8 af[4];
            #pragma unroll
            for (int rf = 0; rf < 4; ++rf)
                af[rf] = *(const bf16x8*)(ab + koff + ((wrow + rf * 16 + lr) << 4));
            #pragma unroll
            for (int rf = 0; rf < 4; ++rf) {
                acc[rf][0] = __builtin_amdgcn_mfma_f32_16x16x32_bf16(af[rf], bR[s * 2],     acc[rf][0], 0, 0, 0);
                acc[rf][1] = __builtin_amdgcn_mfma_f32_16x16x32_bf16(af[rf], bR[s * 2 + 1], acc[rf][1], 0, 0, 0);
            }
        }
    };

    // prologue: stage tile 0
    LOADA(0);
    CVTWRITE(0);
    __syncthreads();

    // per iter: issue B(kt)+A(kt+1) up top (compiler emits exact counted vmcnt at
    // first use of each reg); compute; convert+write next buf; one barrier.
    #pragma unroll
    for (int kt = 0; kt < 8; ++kt) {
        ISSUEB(kt);
        LOADA(kt + 1 < 8 ? kt + 1 : 7);     // kt=7 loads junk -> written to dead buf
        COMPUTE(kt & 1);
        CVTWRITE((kt + 1) & 1);
        __syncthreads();
    }

    // epilogue: bias + relu -> hl[128][256B] swizzled (reuses buf0; overwritten before read)
    char* hl = smem;
    #pragma unroll
    for (int cf = 0; cf < 2; ++cf) {
        const int col = wcol + cf * 16 + lr;
        const float b1v = b1[t * HID + col];
        #pragma unroll
        for (int rf = 0; rf < 4; ++rf)
            #pragma unroll
            for (int q = 0; q < 4; ++q) {
                const int row = wrow + rf * 16 + lg * 4 + q;
                const float hv = fmaxf(acc[rf][cf][q] + b1v, 0.f);
                *(unsigned short*)(hl + row * 256 +
                    (((col >> 3) ^ (row & 7)) << 4) + (col & 7) * 2) = f2bf(hv);
            }
    }
    __syncthreads();

    // GEMM2: [128 x 128] * [128 x 16]; wave wv owns rows wv*16..+15
    const int row2 = wv * 16 + lr;
    f32x4 acc2 = {};
    #pragma unroll
    for (int ks = 0; ks < 4; ++ks) {
        bf16x8 bvv = *(const bf16x8*)(W2t + (((size_t)t * 16 + lr) << 7) + ks * 32 + lg * 8);
        bf16x8 avv = *(const bf16x8*)(hl + row2 * 256 + (((ks * 4 + lg) ^ (row2 & 7)) << 4));
        acc2 = __builtin_amdgcn_mfma_f32_16x16x32_bf16(avv, bvv, acc2, 0, 0, 0);
    }
    if (lr < NCLS) {
        const float b2v = b2[t * NCLS + lr];
        #pragma unroll
        for (int q = 0; q < 4; ++q) {
            const int row = wv * 16 + lg * 4 + q;
            if (row < m) out[(size_t)ridx[row] * NCLS + lr] = acc2[q] + b2v;
        }
    }
}

extern "C" void kernel_launch(void* const* d_in, const int* in_sizes, int n_in,
                              void* d_out, int out_size, void* d_ws, size_t ws_size,
                              hipStream_t stream) {
    (void)in_sizes; (void)n_in; (void)out_size; (void)ws_size;
    const float* x       = (const float*)d_in[0];
    const int*   task_id = (const int*)d_in[1];
    const float* W1      = (const float*)d_in[2];
    const float* b1      = (const float*)d_in[3];
    const float* W2      = (const float*)d_in[4];
    const float* b2      = (const float*)d_in[5];
    float* out = (float*)d_out;
    int* ws = (int*)d_ws;
    hipMemsetAsync(ws, 0, 64, stream);                 // zero cursors
    k_prep<<<784, 256, 0, stream>>>(task_id, W1, W2, ws);
    k_main<<<NTILES, 512, 0, stream>>>(x, b1, b2, ws, out);
}

// Round 16
// 76.692 us; speedup vs baseline: 1.1031x; 1.1031x over previous
//
#include <hip/hip_runtime.h>
#include <hip/hip_bf16.h>

#define TASKS 16
#define DIM 1024
#define HID 128
#define NCLS 10
#define NB 65536
#define BM 128
#define NTILES (NB / BM + TASKS) // 528 = 8 * 66

// ws layout (ints):
//  [0, 4096)            per-block histogram partials [256 blk][16 task]
//  [4096, 4112)         per-task totals
//  [4160, 4160+NB)      rowIdx grouped by task
//  [69696, ...) shorts: W1s [T][32 kstep][8KB tile: [4 kslot][128 col][16B]] (4MB),
//                       then W2t [T][16][128]
#define WS_TOT  4096
#define WS_RIDX 4160
#define WS_W1S  (WS_RIDX + NB)

typedef __attribute__((ext_vector_type(8))) short bf16x8;
typedef __attribute__((ext_vector_type(4))) float f32x4;
typedef __attribute__((ext_vector_type(2))) unsigned u32x2;

__device__ __forceinline__ unsigned short f2bf(float f) {
    union { __hip_bfloat16 h; unsigned short s; } u; u.h = __float2bfloat16(f); return u.s;
}

__device__ __forceinline__ void glds16(const void* gsrc, void* ldst) {
    __builtin_amdgcn_global_load_lds(
        (const __attribute__((address_space(1))) unsigned*)gsrc,
        (__attribute__((address_space(3))) unsigned*)ldst, 16, 0, 0);
}

// ---- pass 1: histogram partials + W1 -> kslot-major bf16 tiles + W2 transpose ----
__global__ __launch_bounds__(256) void k_pre(const int* __restrict__ tid_arr,
                                             const float* __restrict__ W1,
                                             const float* __restrict__ W2,
                                             int* __restrict__ ws) {
    const int blk = blockIdx.x, tid = threadIdx.x;
    if (blk < 256) {
        __shared__ int l[TASKS];
        if (tid < TASKS) l[tid] = 0;
        __syncthreads();
        atomicAdd(&l[tid_arr[blk * 256 + tid]], 1);
        __syncthreads();
        if (tid < TASKS) ws[blk * TASKS + tid] = l[tid];
    } else if (blk < 768) {
        // 8KB tile per (t,kt): [kslot 4][col 128][16B]; k = kt*32 + kslot*8 + j
        const int idx = blk - 256;
        const int t = idx >> 5, kt = idx & 31;
        __shared__ float ld[32 * 132];
        const float* src = W1 + ((size_t)t * DIM + kt * 32) * HID;
        #pragma unroll
        for (int r = 0; r < 16; ++r) {
            const int fl = r * 256 + tid;
            ld[(fl >> 7) * 132 + (fl & 127)] = src[fl];
        }
        __syncthreads();
        char* dst = (char*)((short*)(ws + WS_W1S) + ((size_t)(t * 32 + kt) << 12));
        #pragma unroll
        for (int g = 0; g < 2; ++g) {
            const int p = tid * 32 + g * 16;
            const int kslot = p >> 11, col = (p >> 4) & 127;
            bf16x8 v;
            #pragma unroll
            for (int j = 0; j < 8; ++j)
                v[j] = (short)f2bf(ld[(kslot * 8 + j) * 132 + col]);
            *(bf16x8*)(dst + p) = v;
        }
    } else {
        const int t = blk - 768;
        short* W2t = (short*)(ws + WS_W1S) + ((size_t)TASKS * 32 * 4096);
        #pragma unroll
        for (int i = 0; i < 8; ++i) {
            const int o = i * 256 + tid, c = o >> 7, h = o & 127;
            const float v = (c < NCLS) ? W2[((size_t)t * HID + h) * NCLS + c] : 0.f;
            W2t[((size_t)t * 16 + c) * HID + h] = (short)f2bf(v);
        }
    }
}

// ---- pass 2: deterministic scatter, parallel 2-level prefix ----
__global__ __launch_bounds__(256) void k_scatter(const int* __restrict__ tid_arr,
                                                 int* __restrict__ ws) {
    __shared__ int part[256 * TASKS];
    __shared__ int sums[16 * TASKS];
    __shared__ int l[TASKS], offl[TASKS], prel[TASKS], totl[TASKS];
    const int b = blockIdx.x, tid = threadIdx.x;
    #pragma unroll
    for (int r = 0; r < 16; ++r) part[r * 256 + tid] = ws[r * 256 + tid];
    if (tid < TASKS) l[tid] = 0;
    __syncthreads();
    const int t = tid_arr[b * 256 + tid];
    const int rank = atomicAdd(&l[t], 1);
    {
        const int c = tid >> 4, tt = tid & 15;
        int s = 0;
        #pragma unroll
        for (int bb = 0; bb < 16; ++bb) s += part[(c * 16 + bb) * TASKS + tt];
        sums[c * TASKS + tt] = s;
    }
    __syncthreads();
    if (tid < TASKS) {
        const int cb = b >> 4;
        int pre = 0;
        for (int c = 0; c < cb; ++c) pre += sums[c * TASKS + tid];
        for (int bb = cb * 16; bb < b; ++bb) pre += part[bb * TASKS + tid];
        int tot = 0;
        #pragma unroll
        for (int c = 0; c < 16; ++c) tot += sums[c * TASKS + tid];
        prel[tid] = pre; totl[tid] = tot;
        if (b == 0) ws[WS_TOT + tid] = tot;
    }
    __syncthreads();
    if (tid == 0) {
        int ro = 0;
        for (int k = 0; k < TASKS; ++k) { offl[k] = ro; ro += totl[k]; }
    }
    __syncthreads();
    ws[WS_RIDX + offl[t] + prel[t] + rank] = b * 256 + tid;
}

// ---- pass 3: fused grouped GEMM, 8 waves, conflict-free kslot-major LDS ----
__global__ __launch_bounds__(512, 4) void k_main(
    const float* __restrict__ x, const float* __restrict__ b1,
    const float* __restrict__ b2, const int* __restrict__ ws,
    float* __restrict__ out)
{
    // per buf: A [4 kslot][128 row][16B] = 8KB | B [4 kslot][128 col][16B] = 8KB
    // 2 bufs = 32KB; epilogue reuses as hl[128][256B]
    __shared__ __align__(16) short smem[16384];
    __shared__ int ridx[BM];

    const int* tot = ws + WS_TOT;
    const int* rowIdx = ws + WS_RIDX;
    const short* W1s = (const short*)(ws + WS_W1S);
    const short* W2t = W1s + ((size_t)TASKS * 32 * 4096);

    const int w = (blockIdx.x & 7) * (NTILES / 8) + (blockIdx.x >> 3);

    int t = -1, m = 0, gstart = 0;
    {
        int accT = 0, accO = 0;
        for (int k = 0; k < TASKS; ++k) {
            const int c = tot[k], nt = (c + BM - 1) >> 7;
            if (t < 0 && w < accT + nt) {
                t = k; gstart = accO + (w - accT) * BM;
                m = c - (w - accT) * BM; if (m > BM) m = BM;
            }
            accT += nt; accO += c;
        }
    }
    if (t < 0) return;

    const int tid = threadIdx.x;
    if (tid < BM) ridx[tid] = rowIdx[gstart + (tid < m ? tid : m - 1)];
    __syncthreads();

    const int lane = tid & 63, wv = tid >> 6;          // 8 waves
    const int lg = lane >> 4, lr = lane & 15;
    const int rh = wv & 1, cq = wv >> 1;               // 2 row-halves x 4 col-quarters
    const int wrow = rh * 64, wcol = cq * 32;

    // A staging: wave wv covers rows wv*16..+15; instr j: 8 rows, 8 lanes/row x 16B
    const float* gpA[2];
    unsigned wbA[2];
    #pragma unroll
    for (int j = 0; j < 2; ++j) {
        const int row = wv * 16 + j * 8 + (lane >> 3);
        gpA[j] = x + ((size_t)ridx[row] << 10) + (lane & 7) * 4;
        wbA[j] = ((unsigned)((lane & 7) >> 1)) * 2048 + row * 16 + (lane & 1) * 8;
    }
    // B staging: 1 glds/wave, source sequential in kslot-major W1s
    const char* w1sT = (const char*)W1s + ((size_t)t << 18);

    f32x4 a8[2];
    f32x4 acc[4][2] = {};

    auto LOADA = [&](int kt) {
        #pragma unroll
        for (int j = 0; j < 2; ++j) a8[j] = *(const f32x4*)(gpA[j] + kt * 32);
    };
    auto WRITEA = [&](int buf) {
        char* ab = (char*)smem + buf * 16384;
        #pragma unroll
        for (int j = 0; j < 2; ++j) {
            u32x2 pk;
            pk[0] = ((unsigned)f2bf(a8[j][1]) << 16) | (unsigned)f2bf(a8[j][0]);
            pk[1] = ((unsigned)f2bf(a8[j][3]) << 16) | (unsigned)f2bf(a8[j][2]);
            *(u32x2*)(ab + wbA[j]) = pk;               // ds_write_b64, conflict-free
        }
    };
    auto ISSUEB = [&](int buf, int kt) {
        const char* src = w1sT + ((size_t)kt << 13) + wv * 1024 + lane * 16;
        char* dst = (char*)smem + buf * 16384 + 8192 + wv * 1024;  // wave-uniform
        glds16(src, dst);
    };
    auto COMPUTE = [&](int buf) {
        const char* ab = (const char*)smem + buf * 16384;
        const char* bb = ab + 8192;
        bf16x8 af[4], bfr[2];
        #pragma unroll
        for (int rf = 0; rf < 4; ++rf)
            af[rf] = *(const bf16x8*)(ab + lg * 2048 + (wrow + rf * 16 + lr) * 16);
        #pragma unroll
        for (int cf = 0; cf < 2; ++cf)
            bfr[cf] = *(const bf16x8*)(bb + lg * 2048 + (wcol + cf * 16 + lr) * 16);
        #pragma unroll
        for (int rf = 0; rf < 4; ++rf)
            #pragma unroll
            for (int cf = 0; cf < 2; ++cf)
                acc[rf][cf] = __builtin_amdgcn_mfma_f32_16x16x32_bf16(af[rf], bfr[cf], acc[rf][cf], 0, 0, 0);
    };

    // prologue: in-flight at wait = [g0(1), A1(2)] -> vmcnt(2) drains g0
    LOADA(0);
    ISSUEB(0, 0);
    WRITEA(0);                 // compiler waits A0 only (older than g0)
    LOADA(1);
    asm volatile("s_waitcnt vmcnt(2) lgkmcnt(0)" ::: "memory");
    __builtin_amdgcn_s_barrier();
    __builtin_amdgcn_sched_barrier(0);

    // steady: [A_{kt+1}] -> +g_{kt+1} -> WRITEA waits A -> +A_{kt+2} -> vmcnt(2) drains g
    #pragma unroll 2
    for (int kt = 0; kt < 32; ++kt) {
        const int buf = kt & 1;
        ISSUEB(buf ^ 1, kt + 1 < 32 ? kt + 1 : 31);
        WRITEA(buf ^ 1);
        LOADA(kt + 2 < 32 ? kt + 2 : 31);
        COMPUTE(buf);
        asm volatile("s_waitcnt vmcnt(2) lgkmcnt(0)" ::: "memory");
        __builtin_amdgcn_s_barrier();
        __builtin_amdgcn_sched_barrier(0);
    }
    __syncthreads();   // full drain before LDS reuse

    // epilogue: bias + relu -> hl[128][256B] swizzled
    short* hl = smem;
    #pragma unroll
    for (int cf = 0; cf < 2; ++cf) {
        const int col = wcol + cf * 16 + lr;
        const float b1v = b1[t * HID + col];
        #pragma unroll
        for (int rf = 0; rf < 4; ++rf)
            #pragma unroll
            for (int q = 0; q < 4; ++q) {
                const int row = wrow + rf * 16 + lg * 4 + q;
                const float hv = fmaxf(acc[rf][cf][q] + b1v, 0.f);
                *(unsigned short*)((char*)hl + row * 256 +
                    (((col >> 3) ^ (row & 7)) << 4) + (col & 7) * 2) = f2bf(hv);
            }
    }
    __syncthreads();

    // GEMM2: [128 x 128] * [128 x 16]; wave wv owns rows wv*16..+15
    const int row2 = wv * 16 + lr;
    f32x4 acc2 = {};
    #pragma unroll
    for (int ks = 0; ks < 4; ++ks) {
        bf16x8 bvv = *(const bf16x8*)(W2t + (((size_t)t * 16 + lr) << 7) + ks * 32 + lg * 8);
        bf16x8 avv = *(const bf16x8*)((const char*)hl + row2 * 256 +
                         (((ks * 4 + lg) ^ (row2 & 7)) << 4));
        acc2 = __builtin_amdgcn_mfma_f32_16x16x32_bf16(avv, bvv, acc2, 0, 0, 0);
    }
    if (lr < NCLS) {
        const float b2v = b2[t * NCLS + lr];
        #pragma unroll
        for (int q = 0; q < 4; ++q) {
            const int row = wv * 16 + lg * 4 + q;
            if (row < m) out[(size_t)ridx[row] * NCLS + lr] = acc2[q] + b2v;
        }
    }
}

extern "C" void kernel_launch(void* const* d_in, const int* in_sizes, int n_in,
                              void* d_out, int out_size, void* d_ws, size_t ws_size,
                              hipStream_t stream) {
    (void)in_sizes; (void)n_in; (void)out_size; (void)ws_size;
    const float* x       = (const float*)d_in[0];
    const int*   task_id = (const int*)d_in[1];
    const float* W1      = (const float*)d_in[2];
    const float* b1      = (const float*)d_in[3];
    const float* W2      = (const float*)d_in[4];
    const float* b2      = (const float*)d_in[5];
    float* out = (float*)d_out;
    int* ws = (int*)d_ws;
    k_pre<<<784, 256, 0, stream>>>(task_id, W1, W2, ws);
    k_scatter<<<256, 256, 0, stream>>>(task_id, ws);
    k_main<<<NTILES, 512, 0, stream>>>(x, b1, b2, ws, out);
}